// Round 13
// baseline (231.320 us; speedup 1.0000x reference)
//
#include <hip/hip_runtime.h>
#include <stdint.h>

// Problem constants (match reference)
#define N_NODES  50000
#define N_EDGES  800000
#define D        256
#define D_OUT    16
#define N_GRAPHS 128
#define NB_SCAN  196        // 196*256 = 50176 >= N_NODES+1

// JAX jax_threefry_partitionable=True: bits32(i) = fold(threefry2x32((0,42),(0,i))),
// fold = o0 ^ o1; keep iff top bit == 0.  (verified round 2, absmax 0.0)

typedef short bf16x8 __attribute__((ext_vector_type(8)));
typedef float f32x4  __attribute__((ext_vector_type(4)));

__device__ __forceinline__ uint32_t rotl32(uint32_t x, int d) {
    return (x << d) | (x >> (32 - d));
}

__device__ __forceinline__ void threefry2x32(uint32_t k0, uint32_t k1,
                                             uint32_t c0, uint32_t c1,
                                             uint32_t& o0, uint32_t& o1) {
    uint32_t ks2 = k0 ^ k1 ^ 0x1BD11BDAu;
    uint32_t x0 = c0 + k0, x1 = c1 + k1;
    x0 += x1; x1 = rotl32(x1, 13); x1 ^= x0;
    x0 += x1; x1 = rotl32(x1, 15); x1 ^= x0;
    x0 += x1; x1 = rotl32(x1, 26); x1 ^= x0;
    x0 += x1; x1 = rotl32(x1, 6);  x1 ^= x0;
    x0 += k1; x1 += ks2 + 1u;
    x0 += x1; x1 = rotl32(x1, 17); x1 ^= x0;
    x0 += x1; x1 = rotl32(x1, 29); x1 ^= x0;
    x0 += x1; x1 = rotl32(x1, 16); x1 ^= x0;
    x0 += x1; x1 = rotl32(x1, 24); x1 ^= x0;
    x0 += ks2; x1 += k0 + 2u;
    x0 += x1; x1 = rotl32(x1, 13); x1 ^= x0;
    x0 += x1; x1 = rotl32(x1, 15); x1 ^= x0;
    x0 += x1; x1 = rotl32(x1, 26); x1 ^= x0;
    x0 += x1; x1 = rotl32(x1, 6);  x1 ^= x0;
    x0 += k0; x1 += k1 + 3u;
    x0 += x1; x1 = rotl32(x1, 17); x1 ^= x0;
    x0 += x1; x1 = rotl32(x1, 29); x1 ^= x0;
    x0 += x1; x1 = rotl32(x1, 16); x1 ^= x0;
    x0 += x1; x1 = rotl32(x1, 24); x1 ^= x0;
    x0 += k1; x1 += ks2 + 4u;
    x0 += x1; x1 = rotl32(x1, 13); x1 ^= x0;
    x0 += x1; x1 = rotl32(x1, 15); x1 ^= x0;
    x0 += x1; x1 = rotl32(x1, 26); x1 ^= x0;
    x0 += x1; x1 = rotl32(x1, 6);  x1 ^= x0;
    x0 += ks2; x1 += k0 + 5u;
    o0 = x0; o1 = x1;
}

__device__ __forceinline__ bool dropout_keep(uint32_t i) {
    uint32_t o0, o1;
    threefry2x32(0u, 42u, 0u, i, o0, o1);
    return ((o0 ^ o1) & 0x80000000u) == 0u;
}

// pack keep-bits for elements [i0, i0+8) into one byte
__device__ __forceinline__ uint32_t mask_byte(uint32_t i0) {
    uint32_t b = 0;
#pragma unroll
    for (int k = 0; k < 8; k++)
        b |= (dropout_keep(i0 + k) ? 1u : 0u) << k;
    return b;
}

__device__ __forceinline__ uint32_t bf16_rne(float f) {   // fp32 -> bf16 bits (RNE)
    uint32_t u = __float_as_uint(f);
    return (u + 0x7FFFu + ((u >> 16) & 1u)) >> 16;
}

// blocks 0..15: W[k][n] f32 -> wt[n][k] bf16 (transposed, packed)
// blocks 16..: degsum = 0 (f64), sums = 0
__global__ __launch_bounds__(256) void k_init(const float* __restrict__ W,
                                              ushort* __restrict__ wt,
                                              double* degsum, float* sums) {
    int t = threadIdx.x;
    if (blockIdx.x < 16) {
        __shared__ float td[64][65];
        int kb = blockIdx.x & 3, nb = blockIdx.x >> 2;   // 4x4 tiles of 64x64
        int nl = t & 63, r4 = t >> 6;
#pragma unroll
        for (int i = 0; i < 16; i++) {
            int kl = r4 + 4 * i;
            td[kl][nl] = W[(size_t)(kb * 64 + kl) * 256 + nb * 64 + nl];
        }
        __syncthreads();
        int kp = t & 31, nl2 = t >> 5;
        uint32_t* wt32 = (uint32_t*)wt;
#pragma unroll
        for (int i = 0; i < 8; i++) {
            int n = nl2 + 8 * i;
            uint32_t p = bf16_rne(td[2 * kp][n]) | (bf16_rne(td[2 * kp + 1][n]) << 16);
            wt32[((size_t)(nb * 64 + n) * 256 + kb * 64 + 2 * kp) >> 1] = p;
        }
    } else {
        int i = (blockIdx.x - 16) * 256 + t;
        if (i < N_NODES) degsum[i] = 0.0;
        if (i < N_GRAPHS * D) sums[i] = 0.0f;
    }
}

// ONE f64 atomic per edge (count in high bits, sum ew in fraction)
__global__ __launch_bounds__(256) void k_edeg(const int* __restrict__ ei,
                                              const float* __restrict__ ew,
                                              double* __restrict__ degsum) {
    int e = blockIdx.x * 256 + threadIdx.x;   // grid is exactly 800000 threads
    int c = ei[N_EDGES + e];
    atomicAdd(&degsum[c], 4294967296.0 + (double)ew[e]);
}

// scan phase 1: degsum -> dinv + cnt(start[i]); per-block reduce of counts
__global__ __launch_bounds__(256) void k_scan1(const double* __restrict__ degsum,
                                               float* __restrict__ dinv,
                                               int* __restrict__ start,
                                               int* __restrict__ partial) {
    __shared__ int sd[256];
    int t = threadIdx.x;
    int i = blockIdx.x * 256 + t;
    int cnt = 0;
    if (i < N_NODES) {
        double val = degsum[i];
        cnt = (int)(val * (1.0 / 4294967296.0));          // exact
        float deg = (float)(val - (double)cnt * 4294967296.0) + 1.0f;  // +self-loop
        dinv[i] = rsqrtf(deg);                             // deg >= 1 always
        start[i] = cnt;
    }
    sd[t] = cnt;
    __syncthreads();
    for (int d = 128; d > 0; d >>= 1) {
        if (t < d) sd[t] += sd[t + d];
        __syncthreads();
    }
    if (t == 0) partial[blockIdx.x] = sd[0];
}

// scan phase 2+3 fused: every block redundantly scans the 196 partials in LDS,
// then does its own 256-chunk scan + base offset -> start/cursor (coalesced).
__global__ __launch_bounds__(256) void k_scan3(int* __restrict__ start,
                                               int* __restrict__ cursor,
                                               const int* __restrict__ partial) {
    __shared__ int sp[256];
    __shared__ int so[256];
    __shared__ int sd[256];
    int t = threadIdx.x;
    int pv = (t < NB_SCAN) ? partial[t] : 0;
    sp[t] = pv; so[t] = pv;
    __syncthreads();
    for (int d = 1; d < 256; d <<= 1) {
        int u = (t >= d) ? sp[t - d] : 0;
        __syncthreads();
        sp[t] += u;
        __syncthreads();
    }
    int base = sp[blockIdx.x] - so[blockIdx.x];    // exclusive prefix of this block

    int i = blockIdx.x * 256 + t;
    int v = (i < N_NODES) ? start[i] : 0;
    sd[t] = v;
    __syncthreads();
    for (int d = 1; d < 256; d <<= 1) {
        int u = (t >= d) ? sd[t - d] : 0;
        __syncthreads();
        sd[t] += u;
        __syncthreads();
    }
    int val = base + sd[t] - v;                    // exclusive prefix
    if (i < N_NODES) {
        start[i] = val;
        cursor[i] = val;
    } else if (i == N_NODES) {
        start[N_NODES] = val;                      // == grand total
    }
}

// scatter each edge's (row, RAW ew) into its CSR slot
__global__ __launch_bounds__(256) void k_fill(const int* __restrict__ ei,
                                              const float* __restrict__ ew,
                                              int* __restrict__ cursor,
                                              int2* __restrict__ edge) {
    int e = blockIdx.x * 256 + threadIdx.x;   // grid is exactly 800000 threads
    int r = ei[e];
    int c = ei[N_EDGES + e];
    int pos = atomicAdd(&cursor[c], 1);
    edge[pos] = make_int2(r, __float_as_int(ew[e]));
}

// ---------------- MFMA GEMM: h'(bf16) = dinv[row] * (x @ W1) ---------------
// + dropout-mask epilogue: the mask's threefry VALU co-issues with the MFMA
//   pipe (separate pipes) instead of loading the issue-bound prep kernels.
__device__ __forceinline__ int swz(int row, int kByte) {
    return (row << 9) + (kByte ^ ((row & 7) << 4));
}

__global__ __launch_bounds__(256) void k_gemm(const float* __restrict__ x,
                                              const ushort* __restrict__ wt,
                                              const float* __restrict__ dinv,
                                              ushort* __restrict__ hb,
                                              uint8_t* __restrict__ mask8) {
    __shared__ __align__(16) char smem[65536];   // A: [0,32K), Bt: [32K,64K)
    __shared__ float sdinv[64];
    int tid = threadIdx.x;
    int Mbase = blockIdx.x * 64;

    if (tid < 64) {
        int node = Mbase + tid; if (node >= N_NODES) node = N_NODES - 1;
        sdinv[tid] = dinv[node];
    }
    // ---- stage A: x[Mbase..+63][0..255] -> bf16, swizzled ----
    const float4* xv = (const float4*)x;
#pragma unroll
    for (int i = 0; i < 16; i++) {
        int f = tid + i * 256;        // flat float4 id, 0..4095
        int r = f >> 6;               // row 0..63
        int c4 = f & 63;              // float4 index -> k = 4*c4
        int node = Mbase + r; if (node >= N_NODES) node = N_NODES - 1;
        float4 v = xv[(size_t)node * 64 + c4];
        uint32_t p0 = bf16_rne(v.x) | (bf16_rne(v.y) << 16);
        uint32_t p1 = bf16_rne(v.z) | (bf16_rne(v.w) << 16);
        *(uint2*)(smem + swz(r, c4 * 8)) = make_uint2(p0, p1);
    }

    int l = tid & 63;
    int w = tid >> 6;
    int wr = w >> 1, wc = w & 1;          // wave grid 2x2, each 32x32
    int lr = l & 15;
    int kg = l >> 4;
    int drow = (l >> 4) * 4;
    int dcol = l & 15;
    const uint4* wt4 = (const uint4*)wt;  // 16B units; 32 per 512B row

    for (int nb = 0; nb < 4; nb++) {
        // ---- stage Bt tile: wt rows nb*64..+63 (coalesced uint4 copy) ----
#pragma unroll
        for (int i = 0; i < 8; i++) {
            int f = tid + i * 256;    // 0..2047 uint4
            int r = f >> 5;           // row 0..63
            int c = f & 31;           // 16B chunk
            uint4 v = wt4[(size_t)(nb * 64 + r) * 32 + c];
            *(uint4*)(smem + 32768 + swz(r, c * 16)) = v;
        }
        __syncthreads();

        f32x4 acc00 = {0.f, 0.f, 0.f, 0.f};
        f32x4 acc01 = acc00, acc10 = acc00, acc11 = acc00;
#pragma unroll
        for (int ks = 0; ks < 8; ks++) {
            int kB = ks * 64 + kg * 16;
            bf16x8 a0 = *(const bf16x8*)(smem + swz(wr * 32 + lr, kB));
            bf16x8 a1 = *(const bf16x8*)(smem + swz(wr * 32 + 16 + lr, kB));
            bf16x8 b0 = *(const bf16x8*)(smem + 32768 + swz(wc * 32 + lr, kB));
            bf16x8 b1 = *(const bf16x8*)(smem + 32768 + swz(wc * 32 + 16 + lr, kB));
            acc00 = __builtin_amdgcn_mfma_f32_16x16x32_bf16(a0, b0, acc00, 0, 0, 0);
            acc01 = __builtin_amdgcn_mfma_f32_16x16x32_bf16(a0, b1, acc01, 0, 0, 0);
            acc10 = __builtin_amdgcn_mfma_f32_16x16x32_bf16(a1, b0, acc10, 0, 0, 0);
            acc11 = __builtin_amdgcn_mfma_f32_16x16x32_bf16(a1, b1, acc11, 0, 0, 0);
        }
        // D layout: row=(l>>4)*4+r, col=l&15  (m89-verified); scale by dinv[row]
        int c0 = nb * 64 + wc * 32 + dcol;
#pragma unroll
        for (int r = 0; r < 4; r++) {
            int lr0 = wr * 32 + drow + r;
            int n0 = Mbase + lr0;
            int n1 = n0 + 16;
            float s0 = sdinv[lr0], s1 = sdinv[lr0 + 16];
            if (n0 < N_NODES) {
                hb[(size_t)n0 * 256 + c0]      = (ushort)bf16_rne(acc00[r] * s0);
                hb[(size_t)n0 * 256 + c0 + 16] = (ushort)bf16_rne(acc01[r] * s0);
            }
            if (n1 < N_NODES) {
                hb[(size_t)n1 * 256 + c0]      = (ushort)bf16_rne(acc10[r] * s1);
                hb[(size_t)n1 * 256 + c0 + 16] = (ushort)bf16_rne(acc11[r] * s1);
            }
        }
        __syncthreads();   // Bt reused next iter
    }

    // ---- dropout-mask epilogue: 8 bytes (64 elements) per thread ----
    uint32_t byte0 = (uint32_t)Mbase * 32u + (uint32_t)tid * 8u;
    if (byte0 < (uint32_t)N_NODES * 32u) {
        uint32_t lo = 0, hi = 0;
#pragma unroll
        for (int k = 0; k < 4; k++)
            lo |= mask_byte(byte0 * 8u + (uint32_t)k * 8u) << (8 * k);
#pragma unroll
        for (int k = 0; k < 4; k++)
            hi |= mask_byte(byte0 * 8u + 32u + (uint32_t)k * 8u) << (8 * k);
        *(uint2*)(mask8 + byte0) = make_uint2(lo, hi);
    }
}

// CSR aggregate: fully-masked 8-deep gather pipeline. Per 16-edge chunk,
// lanes 0-31 handle even slots, 32-63 odd slots; 8 × 16B gathers in flight
// per lane (OOB slots clamp to e-1 with weight 0 -> L2-hit dummies).
__device__ __forceinline__ void fma8(float* a, uint4 u, float w) {
    uint32_t p;
    p = u.x;
    a[0] = fmaf(w, __uint_as_float(p << 16), a[0]);
    a[1] = fmaf(w, __uint_as_float(p & 0xffff0000u), a[1]);
    p = u.y;
    a[2] = fmaf(w, __uint_as_float(p << 16), a[2]);
    a[3] = fmaf(w, __uint_as_float(p & 0xffff0000u), a[3]);
    p = u.z;
    a[4] = fmaf(w, __uint_as_float(p << 16), a[4]);
    a[5] = fmaf(w, __uint_as_float(p & 0xffff0000u), a[5]);
    p = u.w;
    a[6] = fmaf(w, __uint_as_float(p << 16), a[6]);
    a[7] = fmaf(w, __uint_as_float(p & 0xffff0000u), a[7]);
}

__global__ __launch_bounds__(256) void k_agg(const int* __restrict__ start,
                                             const int2* __restrict__ edge,
                                             const ushort* __restrict__ hb,
                                             const float* __restrict__ dinv,
                                             const float* __restrict__ b1,
                                             const int* __restrict__ gidx,
                                             const uint8_t* __restrict__ mask8,
                                             float* __restrict__ sums) {
    __shared__ float ls[4][256];
    int wid = threadIdx.x >> 6;
    int l = threadIdx.x & 63;
    int half = l >> 5;                     // 0: even edge slots, 1: odd
    int cl = l & 31;                       // 16B column chunk (cols 8cl..8cl+7)
    int n = blockIdx.x * 4 + wid;          // always < N_NODES
    const uint4* h16 = (const uint4*)hb;   // 32 uint4 per 512B row
    int s = start[n], e = start[n + 1];
    int last = e - 1;

    float a0[8] = {0,0,0,0,0,0,0,0}, a1[8] = {0,0,0,0,0,0,0,0};
    float a2[8] = {0,0,0,0,0,0,0,0}, a3[8] = {0,0,0,0,0,0,0,0};
    for (int j = s; j < e; j += 16) {
        int i0 = j + half;                 // this half's slots: i0 + 2k, k=0..7
        int x0 = i0,      x1 = i0 + 2,  x2 = i0 + 4,  x3 = i0 + 6;
        int x4 = i0 + 8,  x5 = i0 + 10, x6 = i0 + 12, x7 = i0 + 14;
        int c0 = x0 < last ? x0 : last, c1 = x1 < last ? x1 : last;
        int c2 = x2 < last ? x2 : last, c3 = x3 < last ? x3 : last;
        int c4 = x4 < last ? x4 : last, c5 = x5 < last ? x5 : last;
        int c6 = x6 < last ? x6 : last, c7 = x7 < last ? x7 : last;
        int2 E0 = edge[c0], E1 = edge[c1], E2 = edge[c2], E3 = edge[c3];
        int2 E4 = edge[c4], E5 = edge[c5], E6 = edge[c6], E7 = edge[c7];
        uint4 u0 = h16[(size_t)E0.x * 32 + cl];
        uint4 u1 = h16[(size_t)E1.x * 32 + cl];
        uint4 u2 = h16[(size_t)E2.x * 32 + cl];
        uint4 u3 = h16[(size_t)E3.x * 32 + cl];
        uint4 u4 = h16[(size_t)E4.x * 32 + cl];
        uint4 u5 = h16[(size_t)E5.x * 32 + cl];
        uint4 u6 = h16[(size_t)E6.x * 32 + cl];
        uint4 u7 = h16[(size_t)E7.x * 32 + cl];
        float w0 = x0 <= last ? __int_as_float(E0.y) : 0.f;
        float w1 = x1 <= last ? __int_as_float(E1.y) : 0.f;
        float w2 = x2 <= last ? __int_as_float(E2.y) : 0.f;
        float w3 = x3 <= last ? __int_as_float(E3.y) : 0.f;
        float w4 = x4 <= last ? __int_as_float(E4.y) : 0.f;
        float w5 = x5 <= last ? __int_as_float(E5.y) : 0.f;
        float w6 = x6 <= last ? __int_as_float(E6.y) : 0.f;
        float w7 = x7 <= last ? __int_as_float(E7.y) : 0.f;
        fma8(a0, u0, w0); fma8(a1, u1, w1);
        fma8(a2, u2, w2); fma8(a3, u3, w3);
        fma8(a0, u4, w4); fma8(a1, u5, w5);
        fma8(a2, u6, w6); fma8(a3, u7, w7);
    }
    float full[8];
#pragma unroll
    for (int k = 0; k < 8; k++)
        full[k] = (a0[k] + a1[k]) + (a2[k] + a3[k]);
#pragma unroll
    for (int k = 0; k < 8; k++)
        full[k] += __shfl_xor(full[k], 32, 64);   // combine the two edge-halves

    // self-loop + bias + relu + dropout for this lane's 4 cols
    float dn = dinv[n];
    uint4 un = h16[(size_t)n * 32 + cl];
    uint32_t q0 = half ? un.z : un.x;
    uint32_t q1 = half ? un.w : un.y;
    float hn0 = __uint_as_float(q0 << 16);
    float hn1 = __uint_as_float(q0 & 0xffff0000u);
    float hn2 = __uint_as_float(q1 << 16);
    float hn3 = __uint_as_float(q1 & 0xffff0000u);
    int off = 4 * half;
    int col = 8 * cl + off;
    float4 bv = ((const float4*)b1)[2 * cl + half];
    float v0 = fmaxf(dn * (full[off + 0] + hn0) + bv.x, 0.f);
    float v1 = fmaxf(dn * (full[off + 1] + hn1) + bv.y, 0.f);
    float v2 = fmaxf(dn * (full[off + 2] + hn2) + bv.z, 0.f);
    float v3 = fmaxf(dn * (full[off + 3] + hn3) + bv.w, 0.f);
    uint32_t mb = mask8[(size_t)n * 32 + cl];
    v0 = (mb & (1u << (off + 0))) ? v0 * 2.f : 0.f;
    v1 = (mb & (1u << (off + 1))) ? v1 * 2.f : 0.f;
    v2 = (mb & (1u << (off + 2))) ? v2 * 2.f : 0.f;
    v3 = (mb & (1u << (off + 3))) ? v3 * 2.f : 0.f;

    int gfirst = gidx[blockIdx.x * 4];
    int glast  = gidx[blockIdx.x * 4 + 3];
    if (gfirst == glast) {                 // block-uniform branch (~99% of blocks)
        *(float4*)&ls[wid][col] = make_float4(v0, v1, v2, v3);
        __syncthreads();
        int t = threadIdx.x;
        float sv = (ls[0][t] + ls[1][t]) + (ls[2][t] + ls[3][t]);
        atomicAdd(&sums[(size_t)gfirst * D + t], sv);
    } else {                               // graph boundary inside block (rare)
        int g = gidx[n];
        float* sg = &sums[(size_t)g * D + col];
        atomicAdd(sg + 0, v0);
        atomicAdd(sg + 1, v1);
        atomicAdd(sg + 2, v2);
        atomicAdd(sg + 3, v3);
    }
}

// pooled = sums/cnt (cnt via binary search on sorted gidx); out = pooled@fcW+fcb
__global__ __launch_bounds__(256) void k_out(const float* __restrict__ sums,
                                             const int* __restrict__ gidx,
                                             const float* __restrict__ fcW,
                                             const float* __restrict__ fcb,
                                             float* __restrict__ out) {
    __shared__ int sh[2];
    __shared__ float p[D];
    int g = blockIdx.x, t = threadIdx.x;
    if (t == 0) {
        int lo = 0, hi = N_NODES;
        while (lo < hi) { int m = (lo + hi) >> 1; if (gidx[m] < g) lo = m + 1; else hi = m; }
        sh[0] = lo;
        int lo2 = lo; hi = N_NODES;
        while (lo2 < hi) { int m = (lo2 + hi) >> 1; if (gidx[m] < g + 1) lo2 = m + 1; else hi = m; }
        sh[1] = lo2;
    }
    __syncthreads();
    float c = fmaxf((float)(sh[1] - sh[0]), 1.0f);
    p[t] = sums[(size_t)g * D + t] / c;
    __syncthreads();
    if (t < D_OUT) {
        float acc = fcb[t];
        for (int k = 0; k < D; k++)
            acc = fmaf(p[k], fcW[k * D_OUT + t], acc);
        out[g * D_OUT + t] = acc;
    }
}

extern "C" void kernel_launch(void* const* d_in, const int* in_sizes, int n_in,
                              void* d_out, int out_size, void* d_ws, size_t ws_size,
                              hipStream_t stream) {
    const float* x   = (const float*)d_in[0];
    const int*   ei  = (const int*)d_in[1];
    const float* ew  = (const float*)d_in[2];
    const int*   gix = (const int*)d_in[3];
    const float* W1  = (const float*)d_in[4];
    const float* b1  = (const float*)d_in[5];
    const float* fcW = (const float*)d_in[6];
    const float* fcb = (const float*)d_in[7];
    float* out = (float*)d_out;

    float*   ws     = (float*)d_ws;
    float*   dinv   = ws;                                  //    65,536 f
    ushort*  hb     = (ushort*)(ws + 65536);               // 12.8M bf16
    int2*    edge   = (int2*)(ws + 65536 + 6400000);       //   800,000 int2
    int*     start  = (int*)(edge + N_EDGES);              //    65,536
    int*     cursor = start + 65536;                       //    65,536
    int*     partial    = cursor + 65536;                  //       256
    ushort*  wt     = (ushort*)(partial + 512);            //    65,536 us
    float*   sums   = (float*)(wt + 65536);                //    32,768 f
    double*  degsum = (double*)(sums + 32768);             //    50,000 f64
    uint8_t* mask8  = (uint8_t*)(degsum + 50048);          // 1,600,000 B
    // total ~36 MB

    k_init<<<NB_SCAN + 16, 256, 0, stream>>>(W1, wt, degsum, sums);
    k_edeg<<<N_EDGES / 256, 256, 0, stream>>>(ei, ew, degsum);
    k_scan1<<<NB_SCAN, 256, 0, stream>>>(degsum, dinv, start, partial);
    k_scan3<<<NB_SCAN, 256, 0, stream>>>(start, cursor, partial);
    k_fill<<<N_EDGES / 256, 256, 0, stream>>>(ei, ew, cursor, edge);
    k_gemm<<<(N_NODES + 63) / 64, 256, 0, stream>>>(x, wt, dinv, hb, mask8);
    k_agg<<<N_NODES / 4, 256, 0, stream>>>(start, edge, hb, dinv, b1, gix, mask8, sums);
    k_out<<<N_GRAPHS, 256, 0, stream>>>(sums, gix, fcW, fcb, out);
}

// Round 14
// 206.922 us; speedup vs baseline: 1.1179x; 1.1179x over previous
//
#include <hip/hip_runtime.h>
#include <stdint.h>

// Problem constants (match reference)
#define N_NODES  50000
#define N_EDGES  800000
#define D        256
#define D_OUT    16
#define N_GRAPHS 128
#define NB_SCAN  196        // 196*256 = 50176 >= N_NODES+1

// JAX jax_threefry_partitionable=True: bits32(i) = fold(threefry2x32((0,42),(0,i))),
// fold = o0 ^ o1; keep iff top bit == 0.  (verified round 2, absmax 0.0)
// Placement lesson (r11-r13): the 12.8M hashes cost +16us in prep, +15us in
// gemm, +9.7us inline in agg -> inline in agg is the cheapest home.

typedef short bf16x8 __attribute__((ext_vector_type(8)));
typedef float f32x4  __attribute__((ext_vector_type(4)));

__device__ __forceinline__ uint32_t rotl32(uint32_t x, int d) {
    return (x << d) | (x >> (32 - d));
}

__device__ __forceinline__ void threefry2x32(uint32_t k0, uint32_t k1,
                                             uint32_t c0, uint32_t c1,
                                             uint32_t& o0, uint32_t& o1) {
    uint32_t ks2 = k0 ^ k1 ^ 0x1BD11BDAu;
    uint32_t x0 = c0 + k0, x1 = c1 + k1;
    x0 += x1; x1 = rotl32(x1, 13); x1 ^= x0;
    x0 += x1; x1 = rotl32(x1, 15); x1 ^= x0;
    x0 += x1; x1 = rotl32(x1, 26); x1 ^= x0;
    x0 += x1; x1 = rotl32(x1, 6);  x1 ^= x0;
    x0 += k1; x1 += ks2 + 1u;
    x0 += x1; x1 = rotl32(x1, 17); x1 ^= x0;
    x0 += x1; x1 = rotl32(x1, 29); x1 ^= x0;
    x0 += x1; x1 = rotl32(x1, 16); x1 ^= x0;
    x0 += x1; x1 = rotl32(x1, 24); x1 ^= x0;
    x0 += ks2; x1 += k0 + 2u;
    x0 += x1; x1 = rotl32(x1, 13); x1 ^= x0;
    x0 += x1; x1 = rotl32(x1, 15); x1 ^= x0;
    x0 += x1; x1 = rotl32(x1, 26); x1 ^= x0;
    x0 += x1; x1 = rotl32(x1, 6);  x1 ^= x0;
    x0 += k0; x1 += k1 + 3u;
    x0 += x1; x1 = rotl32(x1, 17); x1 ^= x0;
    x0 += x1; x1 = rotl32(x1, 29); x1 ^= x0;
    x0 += x1; x1 = rotl32(x1, 16); x1 ^= x0;
    x0 += x1; x1 = rotl32(x1, 24); x1 ^= x0;
    x0 += k1; x1 += ks2 + 4u;
    x0 += x1; x1 = rotl32(x1, 13); x1 ^= x0;
    x0 += x1; x1 = rotl32(x1, 15); x1 ^= x0;
    x0 += x1; x1 = rotl32(x1, 26); x1 ^= x0;
    x0 += x1; x1 = rotl32(x1, 6);  x1 ^= x0;
    x0 += ks2; x1 += k0 + 5u;
    o0 = x0; o1 = x1;
}

__device__ __forceinline__ bool dropout_keep(uint32_t i) {
    uint32_t o0, o1;
    threefry2x32(0u, 42u, 0u, i, o0, o1);
    return ((o0 ^ o1) & 0x80000000u) == 0u;
}

__device__ __forceinline__ uint32_t bf16_rne(float f) {   // fp32 -> bf16 bits (RNE)
    uint32_t u = __float_as_uint(f);
    return (u + 0x7FFFu + ((u >> 16) & 1u)) >> 16;
}

// blocks 0..15: W[k][n] f32 -> wt[n][k] bf16 (transposed, packed)
// blocks 16..: degsum = 0 (f64), sums = 0
__global__ __launch_bounds__(256) void k_init(const float* __restrict__ W,
                                              ushort* __restrict__ wt,
                                              double* degsum, float* sums) {
    int t = threadIdx.x;
    if (blockIdx.x < 16) {
        __shared__ float td[64][65];
        int kb = blockIdx.x & 3, nb = blockIdx.x >> 2;   // 4x4 tiles of 64x64
        int nl = t & 63, r4 = t >> 6;
#pragma unroll
        for (int i = 0; i < 16; i++) {
            int kl = r4 + 4 * i;
            td[kl][nl] = W[(size_t)(kb * 64 + kl) * 256 + nb * 64 + nl];
        }
        __syncthreads();
        int kp = t & 31, nl2 = t >> 5;
        uint32_t* wt32 = (uint32_t*)wt;
#pragma unroll
        for (int i = 0; i < 8; i++) {
            int n = nl2 + 8 * i;
            uint32_t p = bf16_rne(td[2 * kp][n]) | (bf16_rne(td[2 * kp + 1][n]) << 16);
            wt32[((size_t)(nb * 64 + n) * 256 + kb * 64 + 2 * kp) >> 1] = p;
        }
    } else {
        int i = (blockIdx.x - 16) * 256 + t;
        if (i < N_NODES) degsum[i] = 0.0;
        if (i < N_GRAPHS * D) sums[i] = 0.0f;
    }
}

// ONE f64 atomic per edge (count in high bits, sum ew in fraction)
__global__ __launch_bounds__(256) void k_edeg(const int* __restrict__ ei,
                                              const float* __restrict__ ew,
                                              double* __restrict__ degsum) {
    int e = blockIdx.x * 256 + threadIdx.x;   // grid is exactly 800000 threads
    int c = ei[N_EDGES + e];
    atomicAdd(&degsum[c], 4294967296.0 + (double)ew[e]);
}

// scan phase 1: degsum -> dinv + cnt(start[i]); per-block reduce of counts
__global__ __launch_bounds__(256) void k_scan1(const double* __restrict__ degsum,
                                               float* __restrict__ dinv,
                                               int* __restrict__ start,
                                               int* __restrict__ partial) {
    __shared__ int sd[256];
    int t = threadIdx.x;
    int i = blockIdx.x * 256 + t;
    int cnt = 0;
    if (i < N_NODES) {
        double val = degsum[i];
        cnt = (int)(val * (1.0 / 4294967296.0));          // exact
        float deg = (float)(val - (double)cnt * 4294967296.0) + 1.0f;  // +self-loop
        dinv[i] = rsqrtf(deg);                             // deg >= 1 always
        start[i] = cnt;
    }
    sd[t] = cnt;
    __syncthreads();
    for (int d = 128; d > 0; d >>= 1) {
        if (t < d) sd[t] += sd[t + d];
        __syncthreads();
    }
    if (t == 0) partial[blockIdx.x] = sd[0];
}

// scan phase 2+3 fused: every block redundantly scans the 196 partials in LDS,
// then does its own 256-chunk scan + base offset -> start/cursor (coalesced).
__global__ __launch_bounds__(256) void k_scan3(int* __restrict__ start,
                                               int* __restrict__ cursor,
                                               const int* __restrict__ partial) {
    __shared__ int sp[256];
    __shared__ int so[256];
    __shared__ int sd[256];
    int t = threadIdx.x;
    int pv = (t < NB_SCAN) ? partial[t] : 0;
    sp[t] = pv; so[t] = pv;
    __syncthreads();
    for (int d = 1; d < 256; d <<= 1) {
        int u = (t >= d) ? sp[t - d] : 0;
        __syncthreads();
        sp[t] += u;
        __syncthreads();
    }
    int base = sp[blockIdx.x] - so[blockIdx.x];    // exclusive prefix of this block

    int i = blockIdx.x * 256 + t;
    int v = (i < N_NODES) ? start[i] : 0;
    sd[t] = v;
    __syncthreads();
    for (int d = 1; d < 256; d <<= 1) {
        int u = (t >= d) ? sd[t - d] : 0;
        __syncthreads();
        sd[t] += u;
        __syncthreads();
    }
    int val = base + sd[t] - v;                    // exclusive prefix
    if (i < N_NODES) {
        start[i] = val;
        cursor[i] = val;
    } else if (i == N_NODES) {
        start[N_NODES] = val;                      // == grand total
    }
}

// scatter each edge's (row, RAW ew) into its CSR slot
__global__ __launch_bounds__(256) void k_fill(const int* __restrict__ ei,
                                              const float* __restrict__ ew,
                                              int* __restrict__ cursor,
                                              int2* __restrict__ edge) {
    int e = blockIdx.x * 256 + threadIdx.x;   // grid is exactly 800000 threads
    int r = ei[e];
    int c = ei[N_EDGES + e];
    int pos = atomicAdd(&cursor[c], 1);
    edge[pos] = make_int2(r, __float_as_int(ew[e]));
}

// ---------------- MFMA GEMM: h'(bf16) = dinv[row] * (x @ W1) ---------------
// C-write coalesced through an 8KB LDS staging buffer (2 uint4 stores/thread
// per nb instead of 16 scattered 2B stores). LDS 72KB -> 2 blocks/CU.
__device__ __forceinline__ int swz(int row, int kByte) {
    return (row << 9) + (kByte ^ ((row & 7) << 4));
}

__global__ __launch_bounds__(256) void k_gemm(const float* __restrict__ x,
                                              const ushort* __restrict__ wt,
                                              const float* __restrict__ dinv,
                                              ushort* __restrict__ hb) {
    __shared__ __align__(16) char smem[73728];   // A:[0,32K) Bt:[32K,64K) C:[64K,72K)
    __shared__ float sdinv[64];
    int tid = threadIdx.x;
    int Mbase = blockIdx.x * 64;

    if (tid < 64) {
        int node = Mbase + tid; if (node >= N_NODES) node = N_NODES - 1;
        sdinv[tid] = dinv[node];
    }
    // ---- stage A: x[Mbase..+63][0..255] -> bf16, swizzled ----
    const float4* xv = (const float4*)x;
#pragma unroll
    for (int i = 0; i < 16; i++) {
        int f = tid + i * 256;        // flat float4 id, 0..4095
        int r = f >> 6;               // row 0..63
        int c4 = f & 63;              // float4 index -> k = 4*c4
        int node = Mbase + r; if (node >= N_NODES) node = N_NODES - 1;
        float4 v = xv[(size_t)node * 64 + c4];
        uint32_t p0 = bf16_rne(v.x) | (bf16_rne(v.y) << 16);
        uint32_t p1 = bf16_rne(v.z) | (bf16_rne(v.w) << 16);
        *(uint2*)(smem + swz(r, c4 * 8)) = make_uint2(p0, p1);
    }

    int l = tid & 63;
    int w = tid >> 6;
    int wr = w >> 1, wc = w & 1;          // wave grid 2x2, each 32x32
    int lr = l & 15;
    int kg = l >> 4;
    int drow = (l >> 4) * 4;
    int dcol = l & 15;
    const uint4* wt4 = (const uint4*)wt;  // 16B units; 32 per 512B row
    ushort* c_lds = (ushort*)(smem + 65536);   // [64][64] bf16 tile

    for (int nb = 0; nb < 4; nb++) {
        // ---- stage Bt tile: wt rows nb*64..+63 (coalesced uint4 copy) ----
#pragma unroll
        for (int i = 0; i < 8; i++) {
            int f = tid + i * 256;    // 0..2047 uint4
            int r = f >> 5;           // row 0..63
            int c = f & 31;           // 16B chunk
            uint4 v = wt4[(size_t)(nb * 64 + r) * 32 + c];
            *(uint4*)(smem + 32768 + swz(r, c * 16)) = v;
        }
        __syncthreads();              // Bt ready; prev copy-out done

        f32x4 acc00 = {0.f, 0.f, 0.f, 0.f};
        f32x4 acc01 = acc00, acc10 = acc00, acc11 = acc00;
#pragma unroll
        for (int ks = 0; ks < 8; ks++) {
            int kB = ks * 64 + kg * 16;
            bf16x8 a0 = *(const bf16x8*)(smem + swz(wr * 32 + lr, kB));
            bf16x8 a1 = *(const bf16x8*)(smem + swz(wr * 32 + 16 + lr, kB));
            bf16x8 b0 = *(const bf16x8*)(smem + 32768 + swz(wc * 32 + lr, kB));
            bf16x8 b1 = *(const bf16x8*)(smem + 32768 + swz(wc * 32 + 16 + lr, kB));
            acc00 = __builtin_amdgcn_mfma_f32_16x16x32_bf16(a0, b0, acc00, 0, 0, 0);
            acc01 = __builtin_amdgcn_mfma_f32_16x16x32_bf16(a0, b1, acc01, 0, 0, 0);
            acc10 = __builtin_amdgcn_mfma_f32_16x16x32_bf16(a1, b0, acc10, 0, 0, 0);
            acc11 = __builtin_amdgcn_mfma_f32_16x16x32_bf16(a1, b1, acc11, 0, 0, 0);
        }
        // D layout: row=(l>>4)*4+r, col=l&15 (m89-verified); scale by dinv[row];
        // stage into C_lds for coalesced writeback.
#pragma unroll
        for (int r = 0; r < 4; r++) {
            int lr0 = wr * 32 + drow + r;
            float s0 = sdinv[lr0], s1 = sdinv[lr0 + 16];
            int cc = wc * 32 + dcol;
            c_lds[lr0 * 64 + cc]             = (ushort)bf16_rne(acc00[r] * s0);
            c_lds[lr0 * 64 + cc + 16]        = (ushort)bf16_rne(acc01[r] * s0);
            c_lds[(lr0 + 16) * 64 + cc]      = (ushort)bf16_rne(acc10[r] * s1);
            c_lds[(lr0 + 16) * 64 + cc + 16] = (ushort)bf16_rne(acc11[r] * s1);
        }
        __syncthreads();              // C_lds complete
        // ---- coalesced copy-out: 512 uint4 (8KB), 2 per thread ----
#pragma unroll
        for (int i = 0; i < 2; i++) {
            int idx = tid + i * 256;  // 0..511
            int r = idx >> 3;         // row 0..63 (8 uint4 per 128B row segment)
            int c16 = idx & 7;
            int node = Mbase + r;
            if (node < N_NODES)
                *(uint4*)((char*)hb + (size_t)node * 512 + nb * 128 + c16 * 16) =
                    ((const uint4*)c_lds)[idx];
        }
    }
}

// CSR aggregate: 8-edge batches (4 per 32-lane half, 16B/lane gathers) with
// NEXT-batch edge prefetch overlapping current gathers; threefry dropout
// computed between first-batch issue and the loop (hides initial latency);
// clamp-to-last tail (same line as real last edge -> L1-hit dummies);
// block-level LDS pool flush.
__device__ __forceinline__ void fma8(float* a, uint4 u, float w) {
    uint32_t p;
    p = u.x;
    a[0] = fmaf(w, __uint_as_float(p << 16), a[0]);
    a[1] = fmaf(w, __uint_as_float(p & 0xffff0000u), a[1]);
    p = u.y;
    a[2] = fmaf(w, __uint_as_float(p << 16), a[2]);
    a[3] = fmaf(w, __uint_as_float(p & 0xffff0000u), a[3]);
    p = u.z;
    a[4] = fmaf(w, __uint_as_float(p << 16), a[4]);
    a[5] = fmaf(w, __uint_as_float(p & 0xffff0000u), a[5]);
    p = u.w;
    a[6] = fmaf(w, __uint_as_float(p << 16), a[6]);
    a[7] = fmaf(w, __uint_as_float(p & 0xffff0000u), a[7]);
}

__global__ __launch_bounds__(256) void k_agg(const int* __restrict__ start,
                                             const int2* __restrict__ edge,
                                             const ushort* __restrict__ hb,
                                             const float* __restrict__ dinv,
                                             const float* __restrict__ b1,
                                             const int* __restrict__ gidx,
                                             float* __restrict__ sums) {
    __shared__ float ls[4][256];
    int wid = threadIdx.x >> 6;
    int l = threadIdx.x & 63;
    int half = l >> 5;                     // 0: even edge slots, 1: odd
    int cl = l & 31;                       // 16B column chunk (cols 8cl..8cl+7)
    int n = blockIdx.x * 4 + wid;          // always < N_NODES
    const uint4* h16 = (const uint4*)hb;   // 32 uint4 per 512B row
    int s = start[n], e = start[n + 1];
    int last = e - 1;

    // independent loads issued early
    uint4 un = h16[(size_t)n * 32 + cl];
    float4 bv = ((const float4*)b1)[2 * cl + half];
    float dn = dinv[n];
    int gfirst = gidx[blockIdx.x * 4];
    int glast  = gidx[blockIdx.x * 4 + 3];

    int off = 4 * half;
    int col = 8 * cl + off;

    // first edge batch (clamped) — issue before the threefry block
    int j = s;
    int2 E0, E1, E2, E3;
    if (j < e) {
        int i0 = j + half;
        int x0 = i0, x1 = i0 + 2, x2 = i0 + 4, x3 = i0 + 6;
        E0 = edge[x0 < last ? x0 : last];
        E1 = edge[x1 < last ? x1 : last];
        E2 = edge[x2 < last ? x2 : last];
        E3 = edge[x3 < last ? x3 : last];
    }

    // dropout factors: ~280 VALU instrs hidden under the in-flight loads
    uint32_t base = (uint32_t)n * D + (uint32_t)col;
    float m0 = dropout_keep(base + 0u) ? 2.f : 0.f;
    float m1 = dropout_keep(base + 1u) ? 2.f : 0.f;
    float m2 = dropout_keep(base + 2u) ? 2.f : 0.f;
    float m3 = dropout_keep(base + 3u) ? 2.f : 0.f;

    float a0[8] = {0,0,0,0,0,0,0,0}, a1[8] = {0,0,0,0,0,0,0,0};
    float a2[8] = {0,0,0,0,0,0,0,0}, a3[8] = {0,0,0,0,0,0,0,0};
    for (; j < e; j += 8) {
        int i0 = j + half;
        int x0 = i0, x1 = i0 + 2, x2 = i0 + 4, x3 = i0 + 6;
        // gathers for the current (already-loaded) batch
        uint4 u0 = h16[(size_t)E0.x * 32 + cl];
        uint4 u1 = h16[(size_t)E1.x * 32 + cl];
        uint4 u2 = h16[(size_t)E2.x * 32 + cl];
        uint4 u3 = h16[(size_t)E3.x * 32 + cl];
        float w0 = x0 <= last ? __int_as_float(E0.y) : 0.f;
        float w1 = x1 <= last ? __int_as_float(E1.y) : 0.f;
        float w2 = x2 <= last ? __int_as_float(E2.y) : 0.f;
        float w3 = x3 <= last ? __int_as_float(E3.y) : 0.f;
        // prefetch next batch while gathers are in flight
        int jn = j + 8;
        if (jn < e) {
            int i0n = jn + half;
            int y0 = i0n, y1 = i0n + 2, y2 = i0n + 4, y3 = i0n + 6;
            E0 = edge[y0 < last ? y0 : last];
            E1 = edge[y1 < last ? y1 : last];
            E2 = edge[y2 < last ? y2 : last];
            E3 = edge[y3 < last ? y3 : last];
        }
        fma8(a0, u0, w0); fma8(a1, u1, w1);
        fma8(a2, u2, w2); fma8(a3, u3, w3);
    }
    float full[8];
#pragma unroll
    for (int k = 0; k < 8; k++)
        full[k] = (a0[k] + a1[k]) + (a2[k] + a3[k]);
#pragma unroll
    for (int k = 0; k < 8; k++)
        full[k] += __shfl_xor(full[k], 32, 64);   // combine the two edge-halves

    // self-loop + bias + relu + dropout for this lane's 4 cols
    uint32_t q0 = half ? un.z : un.x;
    uint32_t q1 = half ? un.w : un.y;
    float hn0 = __uint_as_float(q0 << 16);
    float hn1 = __uint_as_float(q0 & 0xffff0000u);
    float hn2 = __uint_as_float(q1 << 16);
    float hn3 = __uint_as_float(q1 & 0xffff0000u);
    float v0 = fmaxf(dn * (full[off + 0] + hn0) + bv.x, 0.f) * m0;
    float v1 = fmaxf(dn * (full[off + 1] + hn1) + bv.y, 0.f) * m1;
    float v2 = fmaxf(dn * (full[off + 2] + hn2) + bv.z, 0.f) * m2;
    float v3 = fmaxf(dn * (full[off + 3] + hn3) + bv.w, 0.f) * m3;

    if (gfirst == glast) {                 // block-uniform branch (~99% of blocks)
        *(float4*)&ls[wid][col] = make_float4(v0, v1, v2, v3);
        __syncthreads();
        int t = threadIdx.x;
        float sv = (ls[0][t] + ls[1][t]) + (ls[2][t] + ls[3][t]);
        atomicAdd(&sums[(size_t)gfirst * D + t], sv);
    } else {                               // graph boundary inside block (rare)
        int g = gidx[n];
        float* sg = &sums[(size_t)g * D + col];
        atomicAdd(sg + 0, v0);
        atomicAdd(sg + 1, v1);
        atomicAdd(sg + 2, v2);
        atomicAdd(sg + 3, v3);
    }
}

// pooled = sums/cnt (cnt via binary search on sorted gidx); out = pooled@fcW+fcb
__global__ __launch_bounds__(256) void k_out(const float* __restrict__ sums,
                                             const int* __restrict__ gidx,
                                             const float* __restrict__ fcW,
                                             const float* __restrict__ fcb,
                                             float* __restrict__ out) {
    __shared__ int sh[2];
    __shared__ float p[D];
    int g = blockIdx.x, t = threadIdx.x;
    if (t == 0) {
        int lo = 0, hi = N_NODES;
        while (lo < hi) { int m = (lo + hi) >> 1; if (gidx[m] < g) lo = m + 1; else hi = m; }
        sh[0] = lo;
        int lo2 = lo; hi = N_NODES;
        while (lo2 < hi) { int m = (lo2 + hi) >> 1; if (gidx[m] < g + 1) lo2 = m + 1; else hi = m; }
        sh[1] = lo2;
    }
    __syncthreads();
    float c = fmaxf((float)(sh[1] - sh[0]), 1.0f);
    p[t] = sums[(size_t)g * D + t] / c;
    __syncthreads();
    if (t < D_OUT) {
        float acc = fcb[t];
        for (int k = 0; k < D; k++)
            acc = fmaf(p[k], fcW[k * D_OUT + t], acc);
        out[g * D_OUT + t] = acc;
    }
}

extern "C" void kernel_launch(void* const* d_in, const int* in_sizes, int n_in,
                              void* d_out, int out_size, void* d_ws, size_t ws_size,
                              hipStream_t stream) {
    const float* x   = (const float*)d_in[0];
    const int*   ei  = (const int*)d_in[1];
    const float* ew  = (const float*)d_in[2];
    const int*   gix = (const int*)d_in[3];
    const float* W1  = (const float*)d_in[4];
    const float* b1  = (const float*)d_in[5];
    const float* fcW = (const float*)d_in[6];
    const float* fcb = (const float*)d_in[7];
    float* out = (float*)d_out;

    float*   ws     = (float*)d_ws;
    float*   dinv   = ws;                                  //    65,536 f
    ushort*  hb     = (ushort*)(ws + 65536);               // 12.8M bf16
    int2*    edge   = (int2*)(ws + 65536 + 6400000);       //   800,000 int2
    int*     start  = (int*)(edge + N_EDGES);              //    65,536
    int*     cursor = start + 65536;                       //    65,536
    int*     partial    = cursor + 65536;                  //       256
    ushort*  wt     = (ushort*)(partial + 512);            //    65,536 us
    float*   sums   = (float*)(wt + 65536);                //    32,768 f
    double*  degsum = (double*)(sums + 32768);             //    50,000 f64
    // total ~35 MB

    k_init<<<NB_SCAN + 16, 256, 0, stream>>>(W1, wt, degsum, sums);
    k_edeg<<<N_EDGES / 256, 256, 0, stream>>>(ei, ew, degsum);
    k_scan1<<<NB_SCAN, 256, 0, stream>>>(degsum, dinv, start, partial);
    k_scan3<<<NB_SCAN, 256, 0, stream>>>(start, cursor, partial);
    k_fill<<<N_EDGES / 256, 256, 0, stream>>>(ei, ew, cursor, edge);
    k_gemm<<<(N_NODES + 63) / 64, 256, 0, stream>>>(x, wt, dinv, hb);
    k_agg<<<N_NODES / 4, 256, 0, stream>>>(start, edge, hb, dinv, b1, gix, sums);
    k_out<<<N_GRAPHS, 256, 0, stream>>>(sums, gix, fcW, fcb, out);
}

// Round 15
// 202.644 us; speedup vs baseline: 1.1415x; 1.0211x over previous
//
#include <hip/hip_runtime.h>
#include <hip/hip_fp16.h>
#include <stdint.h>

// Problem constants (match reference)
#define N_NODES  50000
#define N_EDGES  800000
#define D        256
#define D_OUT    16
#define N_GRAPHS 128
#define NB_SCAN  196        // 196*256 = 50176 >= N_NODES+1

// JAX jax_threefry_partitionable=True: bits32(i) = fold(threefry2x32((0,42),(0,i))),
// fold = o0 ^ o1; keep iff top bit == 0.  (verified round 2, absmax 0.0)
// Placement lesson (r11-r14): inline in agg is the cheapest home for the hashes.
// r15: h stored as fp16; agg inner loop uses v_pk_fma_f16 (halves loop VALU).

typedef short bf16x8 __attribute__((ext_vector_type(8)));
typedef float f32x4  __attribute__((ext_vector_type(4)));

__device__ __forceinline__ uint32_t rotl32(uint32_t x, int d) {
    return (x << d) | (x >> (32 - d));
}

__device__ __forceinline__ void threefry2x32(uint32_t k0, uint32_t k1,
                                             uint32_t c0, uint32_t c1,
                                             uint32_t& o0, uint32_t& o1) {
    uint32_t ks2 = k0 ^ k1 ^ 0x1BD11BDAu;
    uint32_t x0 = c0 + k0, x1 = c1 + k1;
    x0 += x1; x1 = rotl32(x1, 13); x1 ^= x0;
    x0 += x1; x1 = rotl32(x1, 15); x1 ^= x0;
    x0 += x1; x1 = rotl32(x1, 26); x1 ^= x0;
    x0 += x1; x1 = rotl32(x1, 6);  x1 ^= x0;
    x0 += k1; x1 += ks2 + 1u;
    x0 += x1; x1 = rotl32(x1, 17); x1 ^= x0;
    x0 += x1; x1 = rotl32(x1, 29); x1 ^= x0;
    x0 += x1; x1 = rotl32(x1, 16); x1 ^= x0;
    x0 += x1; x1 = rotl32(x1, 24); x1 ^= x0;
    x0 += ks2; x1 += k0 + 2u;
    x0 += x1; x1 = rotl32(x1, 13); x1 ^= x0;
    x0 += x1; x1 = rotl32(x1, 15); x1 ^= x0;
    x0 += x1; x1 = rotl32(x1, 26); x1 ^= x0;
    x0 += x1; x1 = rotl32(x1, 6);  x1 ^= x0;
    x0 += k0; x1 += k1 + 3u;
    x0 += x1; x1 = rotl32(x1, 17); x1 ^= x0;
    x0 += x1; x1 = rotl32(x1, 29); x1 ^= x0;
    x0 += x1; x1 = rotl32(x1, 16); x1 ^= x0;
    x0 += x1; x1 = rotl32(x1, 24); x1 ^= x0;
    x0 += k1; x1 += ks2 + 4u;
    x0 += x1; x1 = rotl32(x1, 13); x1 ^= x0;
    x0 += x1; x1 = rotl32(x1, 15); x1 ^= x0;
    x0 += x1; x1 = rotl32(x1, 26); x1 ^= x0;
    x0 += x1; x1 = rotl32(x1, 6);  x1 ^= x0;
    x0 += ks2; x1 += k0 + 5u;
    o0 = x0; o1 = x1;
}

__device__ __forceinline__ bool dropout_keep(uint32_t i) {
    uint32_t o0, o1;
    threefry2x32(0u, 42u, 0u, i, o0, o1);
    return ((o0 ^ o1) & 0x80000000u) == 0u;
}

__device__ __forceinline__ uint32_t bf16_rne(float f) {   // fp32 -> bf16 bits (RNE)
    uint32_t u = __float_as_uint(f);
    return (u + 0x7FFFu + ((u >> 16) & 1u)) >> 16;
}

// blocks 0..15: W[k][n] f32 -> wt[n][k] bf16 (transposed, packed)
// blocks 16..: degsum = 0 (f64), sums = 0
__global__ __launch_bounds__(256) void k_init(const float* __restrict__ W,
                                              ushort* __restrict__ wt,
                                              double* degsum, float* sums) {
    int t = threadIdx.x;
    if (blockIdx.x < 16) {
        __shared__ float td[64][65];
        int kb = blockIdx.x & 3, nb = blockIdx.x >> 2;   // 4x4 tiles of 64x64
        int nl = t & 63, r4 = t >> 6;
#pragma unroll
        for (int i = 0; i < 16; i++) {
            int kl = r4 + 4 * i;
            td[kl][nl] = W[(size_t)(kb * 64 + kl) * 256 + nb * 64 + nl];
        }
        __syncthreads();
        int kp = t & 31, nl2 = t >> 5;
        uint32_t* wt32 = (uint32_t*)wt;
#pragma unroll
        for (int i = 0; i < 8; i++) {
            int n = nl2 + 8 * i;
            uint32_t p = bf16_rne(td[2 * kp][n]) | (bf16_rne(td[2 * kp + 1][n]) << 16);
            wt32[((size_t)(nb * 64 + n) * 256 + kb * 64 + 2 * kp) >> 1] = p;
        }
    } else {
        int i = (blockIdx.x - 16) * 256 + t;
        if (i < N_NODES) degsum[i] = 0.0;
        if (i < N_GRAPHS * D) sums[i] = 0.0f;
    }
}

// ONE f64 atomic per edge (count in high bits, sum ew in fraction)
__global__ __launch_bounds__(256) void k_edeg(const int* __restrict__ ei,
                                              const float* __restrict__ ew,
                                              double* __restrict__ degsum) {
    int e = blockIdx.x * 256 + threadIdx.x;   // grid is exactly 800000 threads
    int c = ei[N_EDGES + e];
    atomicAdd(&degsum[c], 4294967296.0 + (double)ew[e]);
}

// scan phase 1: degsum -> dinv + cnt(start[i]); per-block reduce of counts
__global__ __launch_bounds__(256) void k_scan1(const double* __restrict__ degsum,
                                               float* __restrict__ dinv,
                                               int* __restrict__ start,
                                               int* __restrict__ partial) {
    __shared__ int sd[256];
    int t = threadIdx.x;
    int i = blockIdx.x * 256 + t;
    int cnt = 0;
    if (i < N_NODES) {
        double val = degsum[i];
        cnt = (int)(val * (1.0 / 4294967296.0));          // exact
        float deg = (float)(val - (double)cnt * 4294967296.0) + 1.0f;  // +self-loop
        dinv[i] = rsqrtf(deg);                             // deg >= 1 always
        start[i] = cnt;
    }
    sd[t] = cnt;
    __syncthreads();
    for (int d = 128; d > 0; d >>= 1) {
        if (t < d) sd[t] += sd[t + d];
        __syncthreads();
    }
    if (t == 0) partial[blockIdx.x] = sd[0];
}

// scan phase 2+3 fused: every block redundantly scans the 196 partials in LDS,
// then does its own 256-chunk scan + base offset -> start/cursor (coalesced).
__global__ __launch_bounds__(256) void k_scan3(int* __restrict__ start,
                                               int* __restrict__ cursor,
                                               const int* __restrict__ partial) {
    __shared__ int sp[256];
    __shared__ int so[256];
    __shared__ int sd[256];
    int t = threadIdx.x;
    int pv = (t < NB_SCAN) ? partial[t] : 0;
    sp[t] = pv; so[t] = pv;
    __syncthreads();
    for (int d = 1; d < 256; d <<= 1) {
        int u = (t >= d) ? sp[t - d] : 0;
        __syncthreads();
        sp[t] += u;
        __syncthreads();
    }
    int base = sp[blockIdx.x] - so[blockIdx.x];    // exclusive prefix of this block

    int i = blockIdx.x * 256 + t;
    int v = (i < N_NODES) ? start[i] : 0;
    sd[t] = v;
    __syncthreads();
    for (int d = 1; d < 256; d <<= 1) {
        int u = (t >= d) ? sd[t - d] : 0;
        __syncthreads();
        sd[t] += u;
        __syncthreads();
    }
    int val = base + sd[t] - v;                    // exclusive prefix
    if (i < N_NODES) {
        start[i] = val;
        cursor[i] = val;
    } else if (i == N_NODES) {
        start[N_NODES] = val;                      // == grand total
    }
}

// scatter each edge's (row, RAW ew) into its CSR slot
__global__ __launch_bounds__(256) void k_fill(const int* __restrict__ ei,
                                              const float* __restrict__ ew,
                                              int* __restrict__ cursor,
                                              int2* __restrict__ edge) {
    int e = blockIdx.x * 256 + threadIdx.x;   // grid is exactly 800000 threads
    int r = ei[e];
    int c = ei[N_EDGES + e];
    int pos = atomicAdd(&cursor[c], 1);
    edge[pos] = make_int2(r, __float_as_int(ew[e]));
}

// ---------------- MFMA GEMM: h'(fp16) = dinv[row] * (x @ W1) ---------------
// MFMA inputs bf16 (as before); OUTPUT stored as fp16 (more accurate than
// bf16, and enables v_pk_fma_f16 in k_agg). Coalesced C-write via 8KB LDS.
__device__ __forceinline__ int swz(int row, int kByte) {
    return (row << 9) + (kByte ^ ((row & 7) << 4));
}

__global__ __launch_bounds__(256) void k_gemm(const float* __restrict__ x,
                                              const ushort* __restrict__ wt,
                                              const float* __restrict__ dinv,
                                              ushort* __restrict__ hb) {
    __shared__ __align__(16) char smem[73728];   // A:[0,32K) Bt:[32K,64K) C:[64K,72K)
    __shared__ float sdinv[64];
    int tid = threadIdx.x;
    int Mbase = blockIdx.x * 64;

    if (tid < 64) {
        int node = Mbase + tid; if (node >= N_NODES) node = N_NODES - 1;
        sdinv[tid] = dinv[node];
    }
    // ---- stage A: x[Mbase..+63][0..255] -> bf16, swizzled ----
    const float4* xv = (const float4*)x;
#pragma unroll
    for (int i = 0; i < 16; i++) {
        int f = tid + i * 256;        // flat float4 id, 0..4095
        int r = f >> 6;               // row 0..63
        int c4 = f & 63;              // float4 index -> k = 4*c4
        int node = Mbase + r; if (node >= N_NODES) node = N_NODES - 1;
        float4 v = xv[(size_t)node * 64 + c4];
        uint32_t p0 = bf16_rne(v.x) | (bf16_rne(v.y) << 16);
        uint32_t p1 = bf16_rne(v.z) | (bf16_rne(v.w) << 16);
        *(uint2*)(smem + swz(r, c4 * 8)) = make_uint2(p0, p1);
    }

    int l = tid & 63;
    int w = tid >> 6;
    int wr = w >> 1, wc = w & 1;          // wave grid 2x2, each 32x32
    int lr = l & 15;
    int kg = l >> 4;
    int drow = (l >> 4) * 4;
    int dcol = l & 15;
    const uint4* wt4 = (const uint4*)wt;  // 16B units; 32 per 512B row
    ushort* c_lds = (ushort*)(smem + 65536);   // [64][64] fp16 tile

    for (int nb = 0; nb < 4; nb++) {
        // ---- stage Bt tile: wt rows nb*64..+63 (coalesced uint4 copy) ----
#pragma unroll
        for (int i = 0; i < 8; i++) {
            int f = tid + i * 256;    // 0..2047 uint4
            int r = f >> 5;           // row 0..63
            int c = f & 31;           // 16B chunk
            uint4 v = wt4[(size_t)(nb * 64 + r) * 32 + c];
            *(uint4*)(smem + 32768 + swz(r, c * 16)) = v;
        }
        __syncthreads();              // Bt ready; prev copy-out done

        f32x4 acc00 = {0.f, 0.f, 0.f, 0.f};
        f32x4 acc01 = acc00, acc10 = acc00, acc11 = acc00;
#pragma unroll
        for (int ks = 0; ks < 8; ks++) {
            int kB = ks * 64 + kg * 16;
            bf16x8 a0 = *(const bf16x8*)(smem + swz(wr * 32 + lr, kB));
            bf16x8 a1 = *(const bf16x8*)(smem + swz(wr * 32 + 16 + lr, kB));
            bf16x8 b0 = *(const bf16x8*)(smem + 32768 + swz(wc * 32 + lr, kB));
            bf16x8 b1 = *(const bf16x8*)(smem + 32768 + swz(wc * 32 + 16 + lr, kB));
            acc00 = __builtin_amdgcn_mfma_f32_16x16x32_bf16(a0, b0, acc00, 0, 0, 0);
            acc01 = __builtin_amdgcn_mfma_f32_16x16x32_bf16(a0, b1, acc01, 0, 0, 0);
            acc10 = __builtin_amdgcn_mfma_f32_16x16x32_bf16(a1, b0, acc10, 0, 0, 0);
            acc11 = __builtin_amdgcn_mfma_f32_16x16x32_bf16(a1, b1, acc11, 0, 0, 0);
        }
        // D layout: row=(l>>4)*4+r, col=l&15 (m89-verified); scale by dinv[row];
        // convert to fp16, stage into C_lds for coalesced writeback.
#pragma unroll
        for (int r = 0; r < 4; r++) {
            int lr0 = wr * 32 + drow + r;
            float s0 = sdinv[lr0], s1 = sdinv[lr0 + 16];
            int cc = wc * 32 + dcol;
            __half h00 = __float2half(acc00[r] * s0);
            __half h01 = __float2half(acc01[r] * s0);
            __half h10 = __float2half(acc10[r] * s1);
            __half h11 = __float2half(acc11[r] * s1);
            c_lds[lr0 * 64 + cc]             = *(ushort*)&h00;
            c_lds[lr0 * 64 + cc + 16]        = *(ushort*)&h01;
            c_lds[(lr0 + 16) * 64 + cc]      = *(ushort*)&h10;
            c_lds[(lr0 + 16) * 64 + cc + 16] = *(ushort*)&h11;
        }
        __syncthreads();              // C_lds complete
        // ---- coalesced copy-out: 512 uint4 (8KB), 2 per thread ----
#pragma unroll
        for (int i = 0; i < 2; i++) {
            int idx = tid + i * 256;  // 0..511
            int r = idx >> 3;         // row 0..63 (8 uint4 per 128B row segment)
            int c16 = idx & 7;
            int node = Mbase + r;
            if (node < N_NODES)
                *(uint4*)((char*)hb + (size_t)node * 512 + nb * 128 + c16 * 16) =
                    ((const uint4*)c_lds)[idx];
        }
    }
}

// CSR aggregate with PACKED fp16 FMA: per uint4 (8 fp16 cols) just 4
// v_pk_fma_f16 ops, no unpack. Edge prefetch + inline threefry (hidden
// under gather latency) + block-level LDS pool flush as in r14.
__device__ __forceinline__ void fma8h(__half2* a, uint4 u, __half2 w) {
    a[0] = __hfma2(*(__half2*)&u.x, w, a[0]);
    a[1] = __hfma2(*(__half2*)&u.y, w, a[1]);
    a[2] = __hfma2(*(__half2*)&u.z, w, a[2]);
    a[3] = __hfma2(*(__half2*)&u.w, w, a[3]);
}

__global__ __launch_bounds__(256) void k_agg(const int* __restrict__ start,
                                             const int2* __restrict__ edge,
                                             const ushort* __restrict__ hb,
                                             const float* __restrict__ dinv,
                                             const float* __restrict__ b1,
                                             const int* __restrict__ gidx,
                                             float* __restrict__ sums) {
    __shared__ float ls[4][256];
    int wid = threadIdx.x >> 6;
    int l = threadIdx.x & 63;
    int half = l >> 5;                     // 0: even edge slots, 1: odd
    int cl = l & 31;                       // 16B column chunk (cols 8cl..8cl+7)
    int n = blockIdx.x * 4 + wid;          // always < N_NODES
    const uint4* h16 = (const uint4*)hb;   // 32 uint4 per 512B row
    int s = start[n], e = start[n + 1];
    int last = e - 1;

    // independent loads issued early
    uint4 un = h16[(size_t)n * 32 + cl];
    float4 bv = ((const float4*)b1)[2 * cl + half];
    float dn = dinv[n];
    int gfirst = gidx[blockIdx.x * 4];
    int glast  = gidx[blockIdx.x * 4 + 3];

    int off = 4 * half;
    int col = 8 * cl + off;

    // first edge batch (clamped) — issue before the threefry block
    int j = s;
    int2 E0, E1, E2, E3;
    if (j < e) {
        int i0 = j + half;
        int x0 = i0, x1 = i0 + 2, x2 = i0 + 4, x3 = i0 + 6;
        E0 = edge[x0 < last ? x0 : last];
        E1 = edge[x1 < last ? x1 : last];
        E2 = edge[x2 < last ? x2 : last];
        E3 = edge[x3 < last ? x3 : last];
    }

    // dropout factors: ~280 VALU instrs hidden under the in-flight loads
    uint32_t base = (uint32_t)n * D + (uint32_t)col;
    float m0 = dropout_keep(base + 0u) ? 2.f : 0.f;
    float m1 = dropout_keep(base + 1u) ? 2.f : 0.f;
    float m2 = dropout_keep(base + 2u) ? 2.f : 0.f;
    float m3 = dropout_keep(base + 3u) ? 2.f : 0.f;

    __half2 z = __float2half2_rn(0.f);
    __half2 A0[4] = {z, z, z, z}, A1[4] = {z, z, z, z};
    __half2 A2[4] = {z, z, z, z}, A3[4] = {z, z, z, z};
    for (; j < e; j += 8) {
        int i0 = j + half;
        int x0 = i0, x1 = i0 + 2, x2 = i0 + 4, x3 = i0 + 6;
        // gathers for the current (already-loaded) batch
        uint4 u0 = h16[(size_t)E0.x * 32 + cl];
        uint4 u1 = h16[(size_t)E1.x * 32 + cl];
        uint4 u2 = h16[(size_t)E2.x * 32 + cl];
        uint4 u3 = h16[(size_t)E3.x * 32 + cl];
        __half2 w0 = __float2half2_rn(x0 <= last ? __int_as_float(E0.y) : 0.f);
        __half2 w1 = __float2half2_rn(x1 <= last ? __int_as_float(E1.y) : 0.f);
        __half2 w2 = __float2half2_rn(x2 <= last ? __int_as_float(E2.y) : 0.f);
        __half2 w3 = __float2half2_rn(x3 <= last ? __int_as_float(E3.y) : 0.f);
        // prefetch next batch while gathers are in flight
        int jn = j + 8;
        if (jn < e) {
            int i0n = jn + half;
            int y0 = i0n, y1 = i0n + 2, y2 = i0n + 4, y3 = i0n + 6;
            E0 = edge[y0 < last ? y0 : last];
            E1 = edge[y1 < last ? y1 : last];
            E2 = edge[y2 < last ? y2 : last];
            E3 = edge[y3 < last ? y3 : last];
        }
        fma8h(A0, u0, w0); fma8h(A1, u1, w1);
        fma8h(A2, u2, w2); fma8h(A3, u3, w3);
    }
    // combine the 4 accumulator sets in f32
    float full[8];
#pragma unroll
    for (int k = 0; k < 4; k++) {
        float lo = (__low2float(A0[k]) + __low2float(A1[k])) +
                   (__low2float(A2[k]) + __low2float(A3[k]));
        float hi = (__high2float(A0[k]) + __high2float(A1[k])) +
                   (__high2float(A2[k]) + __high2float(A3[k]));
        full[2 * k]     = lo;
        full[2 * k + 1] = hi;
    }
#pragma unroll
    for (int k = 0; k < 8; k++)
        full[k] += __shfl_xor(full[k], 32, 64);   // combine the two edge-halves

    // self-loop + bias + relu + dropout for this lane's 4 cols
    uint32_t q0 = half ? un.z : un.x;
    uint32_t q1 = half ? un.w : un.y;
    __half2 hq0 = *(__half2*)&q0;
    __half2 hq1 = *(__half2*)&q1;
    float hn0 = __low2float(hq0), hn1 = __high2float(hq0);
    float hn2 = __low2float(hq1), hn3 = __high2float(hq1);
    float v0 = fmaxf(dn * (full[off + 0] + hn0) + bv.x, 0.f) * m0;
    float v1 = fmaxf(dn * (full[off + 1] + hn1) + bv.y, 0.f) * m1;
    float v2 = fmaxf(dn * (full[off + 2] + hn2) + bv.z, 0.f) * m2;
    float v3 = fmaxf(dn * (full[off + 3] + hn3) + bv.w, 0.f) * m3;

    if (gfirst == glast) {                 // block-uniform branch (~99% of blocks)
        *(float4*)&ls[wid][col] = make_float4(v0, v1, v2, v3);
        __syncthreads();
        int t = threadIdx.x;
        float sv = (ls[0][t] + ls[1][t]) + (ls[2][t] + ls[3][t]);
        atomicAdd(&sums[(size_t)gfirst * D + t], sv);
    } else {                               // graph boundary inside block (rare)
        int g = gidx[n];
        float* sg = &sums[(size_t)g * D + col];
        atomicAdd(sg + 0, v0);
        atomicAdd(sg + 1, v1);
        atomicAdd(sg + 2, v2);
        atomicAdd(sg + 3, v3);
    }
}

// pooled = sums/cnt (cnt via binary search on sorted gidx); out = pooled@fcW+fcb
__global__ __launch_bounds__(256) void k_out(const float* __restrict__ sums,
                                             const int* __restrict__ gidx,
                                             const float* __restrict__ fcW,
                                             const float* __restrict__ fcb,
                                             float* __restrict__ out) {
    __shared__ int sh[2];
    __shared__ float p[D];
    int g = blockIdx.x, t = threadIdx.x;
    if (t == 0) {
        int lo = 0, hi = N_NODES;
        while (lo < hi) { int m = (lo + hi) >> 1; if (gidx[m] < g) lo = m + 1; else hi = m; }
        sh[0] = lo;
        int lo2 = lo; hi = N_NODES;
        while (lo2 < hi) { int m = (lo2 + hi) >> 1; if (gidx[m] < g + 1) lo2 = m + 1; else hi = m; }
        sh[1] = lo2;
    }
    __syncthreads();
    float c = fmaxf((float)(sh[1] - sh[0]), 1.0f);
    p[t] = sums[(size_t)g * D + t] / c;
    __syncthreads();
    if (t < D_OUT) {
        float acc = fcb[t];
        for (int k = 0; k < D; k++)
            acc = fmaf(p[k], fcW[k * D_OUT + t], acc);
        out[g * D_OUT + t] = acc;
    }
}

extern "C" void kernel_launch(void* const* d_in, const int* in_sizes, int n_in,
                              void* d_out, int out_size, void* d_ws, size_t ws_size,
                              hipStream_t stream) {
    const float* x   = (const float*)d_in[0];
    const int*   ei  = (const int*)d_in[1];
    const float* ew  = (const float*)d_in[2];
    const int*   gix = (const int*)d_in[3];
    const float* W1  = (const float*)d_in[4];
    const float* b1  = (const float*)d_in[5];
    const float* fcW = (const float*)d_in[6];
    const float* fcb = (const float*)d_in[7];
    float* out = (float*)d_out;

    float*   ws     = (float*)d_ws;
    float*   dinv   = ws;                                  //    65,536 f
    ushort*  hb     = (ushort*)(ws + 65536);               // 12.8M fp16
    int2*    edge   = (int2*)(ws + 65536 + 6400000);       //   800,000 int2
    int*     start  = (int*)(edge + N_EDGES);              //    65,536
    int*     cursor = start + 65536;                       //    65,536
    int*     partial    = cursor + 65536;                  //       256
    ushort*  wt     = (ushort*)(partial + 512);            //    65,536 us
    float*   sums   = (float*)(wt + 65536);                //    32,768 f
    double*  degsum = (double*)(sums + 32768);             //    50,000 f64
    // total ~35 MB

    k_init<<<NB_SCAN + 16, 256, 0, stream>>>(W1, wt, degsum, sums);
    k_edeg<<<N_EDGES / 256, 256, 0, stream>>>(ei, ew, degsum);
    k_scan1<<<NB_SCAN, 256, 0, stream>>>(degsum, dinv, start, partial);
    k_scan3<<<NB_SCAN, 256, 0, stream>>>(start, cursor, partial);
    k_fill<<<N_EDGES / 256, 256, 0, stream>>>(ei, ew, cursor, edge);
    k_gemm<<<(N_NODES + 63) / 64, 256, 0, stream>>>(x, wt, dinv, hb);
    k_agg<<<N_NODES / 4, 256, 0, stream>>>(start, edge, hb, dinv, b1, gix, sums);
    k_out<<<N_GRAPHS, 256, 0, stream>>>(sums, gix, fcW, fcb, out);
}